// Round 3
// baseline (546.735 us; speedup 1.0000x reference)
//
#include <hip/hip_runtime.h>
#include <math.h>

// ---------------- problem constants ----------------
#define F 32
#define NRBF 20
#define MAXNZ 192
#define PI_F 3.14159265358979323846f

// ---------------- compile-time CG construction ----------------
struct CgCE {
    int cnt;
    int off[10];
    int a[MAXNZ];
    int b[MAXNZ];
    int lb[MAXNZ];
    float v[MAXNZ];
};

constexpr double cfact(int n) { double r = 1.0; for (int i = 2; i <= n; i++) r *= (double)i; return r; }
constexpr double csqrt(double x) {
    if (x <= 0.0) return 0.0;
    double r = x < 1.0 ? 1.0 : x;
    for (int i = 0; i < 80; i++) r = 0.5 * (r + x / r);
    return r;
}
constexpr int cabs_i(int x) { return x < 0 ? -x : x; }

constexpr double cg_c(int j1, int m1, int j2, int m2, int j3, int m3) {
    if (m1 + m2 != m3) return 0.0;
    if (j3 < cabs_i(j1 - j2) || j3 > j1 + j2) return 0.0;
    double pre = csqrt((2.0 * j3 + 1) * cfact(j1 + j2 - j3) * cfact(j1 - j2 + j3) *
                       cfact(-j1 + j2 + j3) / cfact(j1 + j2 + j3 + 1));
    pre *= csqrt(cfact(j3 + m3) * cfact(j3 - m3) * cfact(j1 - m1) * cfact(j1 + m1) *
                 cfact(j2 - m2) * cfact(j2 + m2));
    double s = 0.0;
    for (int k = 0; k <= j1 + j2 + j3; k++) {
        int d0 = k, d1 = j1 + j2 - j3 - k, d2 = j1 - m1 - k, d3 = j2 + m2 - k;
        int d4 = j3 - j2 + m1 + k, d5 = j3 - j1 - m2 + k;
        if (d0 < 0 || d1 < 0 || d2 < 0 || d3 < 0 || d4 < 0 || d5 < 0) continue;
        double t = cfact(d0) * cfact(d1) * cfact(d2) * cfact(d3) * cfact(d4) * cfact(d5);
        s += ((k & 1) ? -1.0 : 1.0) / t;
    }
    return pre * s;
}

struct U5 { double re[5][5]; double im[5][5]; };
constexpr U5 u_real(int l) {
    U5 u{};
    u.re[l][l] = 1.0;
    double s2 = 1.0 / csqrt(2.0);
    for (int m = 1; m <= l; m++) {
        double sgn = (m & 1) ? -1.0 : 1.0;
        u.re[l + m][l + m] = sgn * s2;
        u.re[l + m][l - m] = s2;
        u.im[l - m][l - m] = s2;
        u.im[l - m][l + m] = -sgn * s2;
    }
    return u;
}

struct Dense { double c[9][9][9]; };
constexpr Dense build_dense() {
    Dense D{};
    for (int l1 = 0; l1 <= 2; l1++)
        for (int l2 = 0; l2 <= 2; l2++)
            for (int l3 = 0; l3 <= 2; l3++) {
                if (l3 < cabs_i(l1 - l2) || l3 > l1 + l2) continue;
                U5 U1 = u_real(l1), U2 = u_real(l2), U3 = u_real(l3);
                int n1 = 2 * l1 + 1, n2 = 2 * l2 + 1, n3 = 2 * l3 + 1;
                for (int i = 0; i < n1; i++)
                    for (int j = 0; j < n2; j++) {
                        int k = (i - l1) + (j - l2) + l3;   // m3 = m1+m2
                        if (k < 0 || k >= n3) continue;
                        double C = cg_c(l1, i - l1, l2, j - l2, l3, k - l3);
                        if (C == 0.0) continue;
                        int as[2] = {i, n1 - 1 - i}, bs[2] = {j, n2 - 1 - j}, cs[2] = {k, n3 - 1 - k};
                        int na = (as[0] == as[1]) ? 1 : 2;
                        int nb = (bs[0] == bs[1]) ? 1 : 2;
                        int nc = (cs[0] == cs[1]) ? 1 : 2;
                        for (int ai = 0; ai < na; ai++)
                            for (int bi = 0; bi < nb; bi++)
                                for (int ci = 0; ci < nc; ci++) {
                                    int aa = as[ai], bb = bs[bi], cc = cs[ci];
                                    double xr = U1.re[aa][i], xi = U1.im[aa][i];
                                    double yr = U2.re[bb][j], yi = U2.im[bb][j];
                                    double tr = xr * yr - xi * yi;
                                    double ti = xr * yi + xi * yr;
                                    double zr = U3.re[cc][k], zi = -U3.im[cc][k]; // conj
                                    double add = (tr * zr - ti * zi) * C;
                                    if (add != 0.0)
                                        D.c[l1 * l1 + aa][l2 * l2 + bb][l3 * l3 + cc] += add;
                                }
                    }
            }
    return D;
}

constexpr CgCE build_cg() {
    CgCE t{};
    Dense D = build_dense();
    int cnt = 0;
    for (int o = 0; o < 9; o++) {
        t.off[o] = cnt;
        for (int aa = 0; aa < 9; aa++)
            for (int bb = 0; bb < 9; bb++) {
                double v = D.c[aa][bb][o];
                if (v > 1e-10 || v < -1e-10) {
                    t.a[cnt] = aa;
                    t.b[cnt] = bb;
                    t.lb[cnt] = (bb == 0) ? 0 : ((bb < 4) ? 1 : 2);
                    t.v[cnt] = (float)v;
                    cnt++;
                }
            }
    }
    t.off[9] = cnt;
    t.cnt = cnt;
    return t;
}

constexpr CgCE CG = build_cg();
static_assert(CG.cnt <= MAXNZ, "CG nnz overflow");
static_assert(CG.cnt > 0, "CG empty");

// ---------------- helpers ----------------
__device__ inline float readlane_f(float v, int lane) {
    union { float f; int i; } u; u.f = v;
    int r = __builtin_amdgcn_readlane(u.i, lane);
    union { int i; float f; } w; w.i = r;
    return w.f;
}

// ---------------- device kernels ----------------

__global__ void init_x_kernel(float* __restrict__ x, const int* __restrict__ Z,
                              const float* __restrict__ emb, int N) {
    int idx = blockIdx.x * blockDim.x + threadIdx.x;
    if (idx >= N * 288) return;
    int n = idx / 288, r = idx % 288;
    x[idx] = (r < F) ? emb[Z[n] * F + r] : 0.0f;
}

__global__ void geom_kernel(const float* __restrict__ rij,
                            float* __restrict__ rad, float* __restrict__ cutv, int E) {
    int e = blockIdx.x * blockDim.x + threadIdx.x;
    if (e >= E) return;
    float x = rij[e * 3 + 0], y = rij[e * 3 + 1], z = rij[e * 3 + 2];
    float d = sqrtf(x * x + y * y + z * z);
    const float step = 5.0f / 19.0f;
    const float coeff = -0.5f / (step * step);
    float* re = rad + (size_t)e * NRBF;
    #pragma unroll
    for (int r = 0; r < NRBF; r++) {
        float t = d - step * (float)r;
        re[r] = expf(coeff * t * t);
    }
    cutv[e] = (d < 5.0f) ? 0.5f * (cosf(d * PI_F / 5.0f) + 1.0f) : 0.0f;
}

__global__ void hist_kernel(const int* __restrict__ idx_i, int* __restrict__ deg, int E) {
    int e = blockIdx.x * blockDim.x + threadIdx.x;
    if (e < E) atomicAdd(&deg[idx_i[e]], 1);
}

#define SCAN_T 1024
__global__ __launch_bounds__(SCAN_T) void scan_kernel(
    const int* __restrict__ deg, int* __restrict__ rowptr,
    int* __restrict__ cursor, int N) {
    __shared__ int part[SCAN_T];
    int t = threadIdx.x;
    int per = (N + SCAN_T - 1) / SCAN_T;
    int lo = t * per, hi = lo + per;
    if (hi > N) hi = N;
    int s = 0;
    for (int i = lo; i < hi; i++) s += deg[i];
    part[t] = s;
    __syncthreads();
    for (int off = 1; off < SCAN_T; off <<= 1) {
        int v = (t >= off) ? part[t - off] : 0;
        __syncthreads();
        part[t] += v;
        __syncthreads();
    }
    int run = (t == 0) ? 0 : part[t - 1];
    for (int i = lo; i < hi; i++) {
        rowptr[i] = run;
        cursor[i] = run;
        run += deg[i];
    }
    if (t == SCAN_T - 1) rowptr[N] = run;
}

__global__ void scatter_kernel(const int* __restrict__ idx_i, int* __restrict__ cursor,
                               int* __restrict__ esort, int E) {
    int e = blockIdx.x * blockDim.x + threadIdx.x;
    if (e >= E) return;
    int p = atomicAdd(&cursor[idx_i[e]], 1);
    esort[p] = e;
}

// fused per-layer kernel: one wave per node; two halves process two edges
// per iteration; mixing matmuls broadcast via v_readlane.
__global__ __launch_bounds__(256, 4) void layer_kernel(
    const float* __restrict__ xin, float* __restrict__ xout,
    const float* __restrict__ rij, const float* __restrict__ radb,
    const float* __restrict__ cutb,
    const int* __restrict__ rowptr, const int* __restrict__ esort,
    const int* __restrict__ idx_j,
    const float* __restrict__ fw, const float* __restrict__ fb,
    const float* __restrict__ m1w, const float* __restrict__ m2w,
    const float* __restrict__ m3w,
    const float* __restrict__ gw, const float* __restrict__ gbias, int N) {

    int lane = threadIdx.x & 63;
    int h = lane >> 5;
    int f = lane & 31;
    int n = blockIdx.x * 4 + (threadIdx.x >> 6);

    float frw[NRBF * 3];
    #pragma unroll
    for (int r = 0; r < NRBF; r++)
        #pragma unroll
        for (int lc = 0; lc < 3; lc++)
            frw[r * 3 + lc] = fw[r * 96 + lc * F + f];
    float fb0 = fb[f], fb1 = fb[F + f], fb2 = fb[2 * F + f];

    if (n >= N) return;

    float msg[9];
    #pragma unroll
    for (int o = 0; o < 9; o++) msg[o] = 0.0f;

    int start = rowptr[n], end = rowptr[n + 1];
    for (int k = start + h; k < end; k += 2) {
        int e = esort[k];
        const float* re = radb + (size_t)e * NRBF;
        float W0 = fb0, W1 = fb1, W2 = fb2;
        #pragma unroll
        for (int q = 0; q < 5; q++) {
            float4 rv = *(const float4*)&re[q * 4];
            float rr[4] = {rv.x, rv.y, rv.z, rv.w};
            #pragma unroll
            for (int jj = 0; jj < 4; jj++) {
                int r = q * 4 + jj;
                W0 += rr[jj] * frw[r * 3 + 0];
                W1 += rr[jj] * frw[r * 3 + 1];
                W2 += rr[jj] * frw[r * 3 + 2];
            }
        }
        float cu = cutb[e];
        W0 *= cu; W1 *= cu; W2 *= cu;

        float rx = rij[3 * e + 0], ry = rij[3 * e + 1], rz = rij[3 * e + 2];
        float dd = sqrtf(rx * rx + ry * ry + rz * rz);
        float inv = 1.0f / dd;
        rx *= inv; ry *= inv; rz *= inv;
        const float c0 = 0.28209479177387814f, c1 = 0.4886025119029199f;
        const float c2 = 1.0925484305920792f, c20 = 0.31539156525252005f;
        const float c22 = 0.5462742152960396f;
        float T[9];
        T[0] = c0 * W0;
        T[1] = c1 * ry * W1;
        T[2] = c1 * rz * W1;
        T[3] = c1 * rx * W1;
        T[4] = c2 * rx * ry * W2;
        T[5] = c2 * ry * rz * W2;
        T[6] = c20 * (3.0f * rz * rz - 1.0f) * W2;
        T[7] = c2 * rx * rz * W2;
        T[8] = c22 * (rx * rx - ry * ry) * W2;

        int j = idx_j[e];
        const float* xjp = xin + (size_t)j * 288;
        float xj[9];
        #pragma unroll
        for (int m = 0; m < 9; m++) xj[m] = xjp[m * F + f];

        #pragma unroll
        for (int o = 0; o < 9; o++) {
            float acc = msg[o];
            #pragma unroll
            for (int t = CG.off[o]; t < CG.off[o + 1]; t++)
                acc += (xj[CG.a[t]] * T[CG.b[t]]) * CG.v[t];
            msg[o] = acc;
        }
    }

    #pragma unroll
    for (int o = 0; o < 9; o++)
        msg[o] += __shfl_xor(msg[o], 32, 64);

    // ---------- node mixing ----------
    float wreg[F];

    #pragma unroll
    for (int g = 0; g < F; g++) wreg[g] = m1w[g * F + f];
    float ddx[9];
    #pragma unroll
    for (int m = 0; m < 9; m++) ddx[m] = 0.0f;
    #pragma unroll
    for (int g = 0; g < F; g++) {
        #pragma unroll
        for (int m = 0; m < 9; m++)
            ddx[m] += readlane_f(msg[m], g) * wreg[g];
    }

    float tr[9];
    #pragma unroll
    for (int o = 0; o < 9; o++) {
        float acc = 0.0f;
        #pragma unroll
        for (int t = CG.off[o]; t < CG.off[o + 1]; t++)
            acc += msg[CG.a[t]] * ddx[CG.b[t]] * CG.v[t];
        tr[o] = msg[o] + acc;
    }

    #pragma unroll
    for (int g = 0; g < F; g++) wreg[g] = m2w[g * F + f];
    float dx2[9];
    #pragma unroll
    for (int m = 0; m < 9; m++) dx2[m] = 0.0f;
    #pragma unroll
    for (int g = 0; g < F; g++) {
        #pragma unroll
        for (int m = 0; m < 9; m++)
            dx2[m] += readlane_f(tr[m], g) * wreg[g];
    }

    float ga0 = gbias[f], ga1 = gbias[F + f], ga2 = gbias[2 * F + f];
    #pragma unroll
    for (int g = 0; g < F; g++) {
        float s = readlane_f(dx2[0], g);
        ga0 += s * gw[g * 96 + 0 * F + f];
        ga1 += s * gw[g * 96 + 1 * F + f];
        ga2 += s * gw[g * 96 + 2 * F + f];
    }
    float s0 = 1.0f / (1.0f + expf(-ga0));
    float s1 = 1.0f / (1.0f + expf(-ga1));
    float s2 = 1.0f / (1.0f + expf(-ga2));

    float gt[9];
    gt[0] = dx2[0] * s0;
    gt[1] = dx2[1] * s1; gt[2] = dx2[2] * s1; gt[3] = dx2[3] * s1;
    gt[4] = dx2[4] * s2; gt[5] = dx2[5] * s2; gt[6] = dx2[6] * s2;
    gt[7] = dx2[7] * s2; gt[8] = dx2[8] * s2;

    #pragma unroll
    for (int g = 0; g < F; g++) wreg[g] = m3w[g * F + f];
    float outv[9];
    #pragma unroll
    for (int m = 0; m < 9; m++) outv[m] = 0.0f;
    #pragma unroll
    for (int g = 0; g < F; g++) {
        #pragma unroll
        for (int m = 0; m < 9; m++)
            outv[m] += readlane_f(gt[m], g) * wreg[g];
    }

    if (h == 0) {
        const float* xip = xin + (size_t)n * 288;
        float* xop = xout + (size_t)n * 288;
        #pragma unroll
        for (int m = 0; m < 9; m++)
            xop[m * F + f] = xip[m * F + f] + outv[m];
    }
}

// ---------------- launch ----------------
extern "C" void kernel_launch(void* const* d_in, const int* in_sizes, int n_in,
                              void* d_out, int out_size, void* d_ws, size_t ws_size,
                              hipStream_t stream) {
    int N = in_sizes[0];
    int E = in_sizes[2];
    int L = in_sizes[5] / (NRBF * 3 * F);

    const int* Z = (const int*)d_in[0];
    const float* rij = (const float*)d_in[1];
    const int* idx_i = (const int*)d_in[2];
    const int* idx_j = (const int*)d_in[3];
    const float* emb = (const float*)d_in[4];
    const float* filt_w = (const float*)d_in[5];
    const float* filt_b = (const float*)d_in[6];
    const float* m1w = (const float*)d_in[7];
    const float* m2w = (const float*)d_in[8];
    const float* m3w = (const float*)d_in[9];
    const float* gw = (const float*)d_in[10];
    const float* gb = (const float*)d_in[11];

    float* ws = (float*)d_ws;
    float* radb = ws;                        // E*20
    float* cutb = radb + (size_t)E * NRBF;   // E
    float* xalt = cutb + E;                  // N*288
    int* deg = (int*)(xalt + (size_t)N * 288);  // N
    int* rowptr = deg + N;                   // N+1
    int* cursor = rowptr + N + 1;            // N
    int* esort = cursor + N;                 // E

    float* bufs[2];
    bufs[0] = (L % 2 == 0) ? (float*)d_out : xalt;
    bufs[1] = (L % 2 == 0) ? xalt : (float*)d_out;

    init_x_kernel<<<(N * 288 + 255) / 256, 256, 0, stream>>>(bufs[0], Z, emb, N);
    geom_kernel<<<(E + 255) / 256, 256, 0, stream>>>(rij, radb, cutb, E);

    hipMemsetAsync(deg, 0, (size_t)N * sizeof(int), stream);
    hist_kernel<<<(E + 255) / 256, 256, 0, stream>>>(idx_i, deg, E);
    scan_kernel<<<1, SCAN_T, 0, stream>>>(deg, rowptr, cursor, N);
    scatter_kernel<<<(E + 255) / 256, 256, 0, stream>>>(idx_i, cursor, esort, E);

    for (int li = 0; li < L; li++) {
        layer_kernel<<<(N + 3) / 4, 256, 0, stream>>>(
            bufs[li % 2], bufs[(li + 1) % 2], rij, radb, cutb,
            rowptr, esort, idx_j,
            filt_w + (size_t)li * NRBF * 96, filt_b + (size_t)li * 96,
            m1w + (size_t)li * F * F, m2w + (size_t)li * F * F,
            m3w + (size_t)li * F * F, gw + (size_t)li * F * 96,
            gb + (size_t)li * 96, N);
    }
}

// Round 4
// 507.035 us; speedup vs baseline: 1.0783x; 1.0783x over previous
//
#include <hip/hip_runtime.h>
#include <math.h>

// ---------------- problem constants ----------------
#define F 32
#define NRBF 20
#define MAXNZ 192
#define NB 4
#define PI_F 3.14159265358979323846f

// ---------------- compile-time CG construction ----------------
struct CgCE {
    int cnt;
    int off[10];
    int a[MAXNZ];
    int b[MAXNZ];
    int lb[MAXNZ];
    float v[MAXNZ];
};

constexpr double cfact(int n) { double r = 1.0; for (int i = 2; i <= n; i++) r *= (double)i; return r; }
constexpr double csqrt(double x) {
    if (x <= 0.0) return 0.0;
    double r = x < 1.0 ? 1.0 : x;
    for (int i = 0; i < 80; i++) r = 0.5 * (r + x / r);
    return r;
}
constexpr int cabs_i(int x) { return x < 0 ? -x : x; }

constexpr double cg_c(int j1, int m1, int j2, int m2, int j3, int m3) {
    if (m1 + m2 != m3) return 0.0;
    if (j3 < cabs_i(j1 - j2) || j3 > j1 + j2) return 0.0;
    double pre = csqrt((2.0 * j3 + 1) * cfact(j1 + j2 - j3) * cfact(j1 - j2 + j3) *
                       cfact(-j1 + j2 + j3) / cfact(j1 + j2 + j3 + 1));
    pre *= csqrt(cfact(j3 + m3) * cfact(j3 - m3) * cfact(j1 - m1) * cfact(j1 + m1) *
                 cfact(j2 - m2) * cfact(j2 + m2));
    double s = 0.0;
    for (int k = 0; k <= j1 + j2 + j3; k++) {
        int d0 = k, d1 = j1 + j2 - j3 - k, d2 = j1 - m1 - k, d3 = j2 + m2 - k;
        int d4 = j3 - j2 + m1 + k, d5 = j3 - j1 - m2 + k;
        if (d0 < 0 || d1 < 0 || d2 < 0 || d3 < 0 || d4 < 0 || d5 < 0) continue;
        double t = cfact(d0) * cfact(d1) * cfact(d2) * cfact(d3) * cfact(d4) * cfact(d5);
        s += ((k & 1) ? -1.0 : 1.0) / t;
    }
    return pre * s;
}

struct U5 { double re[5][5]; double im[5][5]; };
constexpr U5 u_real(int l) {
    U5 u{};
    u.re[l][l] = 1.0;
    double s2 = 1.0 / csqrt(2.0);
    for (int m = 1; m <= l; m++) {
        double sgn = (m & 1) ? -1.0 : 1.0;
        u.re[l + m][l + m] = sgn * s2;
        u.re[l + m][l - m] = s2;
        u.im[l - m][l - m] = s2;
        u.im[l - m][l + m] = -sgn * s2;
    }
    return u;
}

struct Dense { double c[9][9][9]; };
constexpr Dense build_dense() {
    Dense D{};
    for (int l1 = 0; l1 <= 2; l1++)
        for (int l2 = 0; l2 <= 2; l2++)
            for (int l3 = 0; l3 <= 2; l3++) {
                if (l3 < cabs_i(l1 - l2) || l3 > l1 + l2) continue;
                U5 U1 = u_real(l1), U2 = u_real(l2), U3 = u_real(l3);
                int n1 = 2 * l1 + 1, n2 = 2 * l2 + 1, n3 = 2 * l3 + 1;
                for (int i = 0; i < n1; i++)
                    for (int j = 0; j < n2; j++) {
                        int k = (i - l1) + (j - l2) + l3;   // m3 = m1+m2
                        if (k < 0 || k >= n3) continue;
                        double C = cg_c(l1, i - l1, l2, j - l2, l3, k - l3);
                        if (C == 0.0) continue;
                        int as[2] = {i, n1 - 1 - i}, bs[2] = {j, n2 - 1 - j}, cs[2] = {k, n3 - 1 - k};
                        int na = (as[0] == as[1]) ? 1 : 2;
                        int nb = (bs[0] == bs[1]) ? 1 : 2;
                        int nc = (cs[0] == cs[1]) ? 1 : 2;
                        for (int ai = 0; ai < na; ai++)
                            for (int bi = 0; bi < nb; bi++)
                                for (int ci = 0; ci < nc; ci++) {
                                    int aa = as[ai], bb = bs[bi], cc = cs[ci];
                                    double xr = U1.re[aa][i], xi = U1.im[aa][i];
                                    double yr = U2.re[bb][j], yi = U2.im[bb][j];
                                    double tr = xr * yr - xi * yi;
                                    double ti = xr * yi + xi * yr;
                                    double zr = U3.re[cc][k], zi = -U3.im[cc][k]; // conj
                                    double add = (tr * zr - ti * zi) * C;
                                    if (add != 0.0)
                                        D.c[l1 * l1 + aa][l2 * l2 + bb][l3 * l3 + cc] += add;
                                }
                    }
            }
    return D;
}

constexpr CgCE build_cg() {
    CgCE t{};
    Dense D = build_dense();
    int cnt = 0;
    for (int o = 0; o < 9; o++) {
        t.off[o] = cnt;
        for (int aa = 0; aa < 9; aa++)
            for (int bb = 0; bb < 9; bb++) {
                double v = D.c[aa][bb][o];
                if (v > 1e-10 || v < -1e-10) {
                    t.a[cnt] = aa;
                    t.b[cnt] = bb;
                    t.lb[cnt] = (bb == 0) ? 0 : ((bb < 4) ? 1 : 2);
                    t.v[cnt] = (float)v;
                    cnt++;
                }
            }
    }
    t.off[9] = cnt;
    t.cnt = cnt;
    return t;
}

constexpr CgCE CG = build_cg();
static_assert(CG.cnt <= MAXNZ, "CG nnz overflow");
static_assert(CG.cnt > 0, "CG empty");

// ---------------- device kernels ----------------

__global__ void init_x_kernel(float* __restrict__ x, const int* __restrict__ Z,
                              const float* __restrict__ emb, int N) {
    int idx = blockIdx.x * blockDim.x + threadIdx.x;
    if (idx >= N * 288) return;
    int n = idx / 288, r = idx % 288;
    x[idx] = (r < F) ? emb[Z[n] * F + r] : 0.0f;
}

// per-(edge,feature): W[e][3][32] = (rad(d) @ fw + fb) * cut(d), per layer.
__global__ __launch_bounds__(256) void geomW_kernel(
    const float* __restrict__ rij, const float* __restrict__ fw,
    const float* __restrict__ fbias, float* __restrict__ Wbuf, int E) {
    int t = blockIdx.x * blockDim.x + threadIdx.x;
    int e = t >> 5, f = t & 31;
    if (e >= E) return;
    float rx = rij[3 * e + 0], ry = rij[3 * e + 1], rz = rij[3 * e + 2];
    float d = sqrtf(rx * rx + ry * ry + rz * rz);
    const float step = 5.0f / 19.0f;
    const float coeff = -0.5f / (step * step);
    float W0 = fbias[f], W1 = fbias[F + f], W2 = fbias[2 * F + f];
    #pragma unroll
    for (int r = 0; r < NRBF; r++) {
        float tt = d - step * (float)r;
        float rv = expf(coeff * tt * tt);
        W0 += rv * fw[r * 96 + f];
        W1 += rv * fw[r * 96 + F + f];
        W2 += rv * fw[r * 96 + 2 * F + f];
    }
    float cu = (d < 5.0f) ? 0.5f * (cosf(d * PI_F / 5.0f) + 1.0f) : 0.0f;
    float* wp = Wbuf + (size_t)e * 96;
    wp[f] = W0 * cu;
    wp[F + f] = W1 * cu;
    wp[2 * F + f] = W2 * cu;
}

// ---- CSR build ----
__global__ void hist_kernel(const int* __restrict__ idx_i, int* __restrict__ deg, int E) {
    int e = blockIdx.x * blockDim.x + threadIdx.x;
    if (e < E) atomicAdd(&deg[idx_i[e]], 1);
}

#define SCAN_T 1024
__global__ __launch_bounds__(SCAN_T) void scan_kernel(
    const int* __restrict__ deg, int* __restrict__ rowptr,
    int* __restrict__ cursor, int N) {
    __shared__ int part[SCAN_T];
    int t = threadIdx.x;
    int per = (N + SCAN_T - 1) / SCAN_T;
    int lo = t * per, hi = lo + per;
    if (hi > N) hi = N;
    int s = 0;
    for (int i = lo; i < hi; i++) s += deg[i];
    part[t] = s;
    __syncthreads();
    for (int off = 1; off < SCAN_T; off <<= 1) {
        int v = (t >= off) ? part[t - off] : 0;
        __syncthreads();
        part[t] += v;
        __syncthreads();
    }
    int run = (t == 0) ? 0 : part[t - 1];
    for (int i = lo; i < hi; i++) {
        rowptr[i] = run;
        cursor[i] = run;
        run += deg[i];
    }
    if (t == SCAN_T - 1) rowptr[N] = run;
}

__global__ void scatter_kernel(const int* __restrict__ idx_i, int* __restrict__ cursor,
                               int* __restrict__ esort, int E) {
    int e = blockIdx.x * blockDim.x + threadIdx.x;
    if (e >= E) return;
    int p = atomicAdd(&cursor[idx_i[e]], 1);
    esort[p] = e;
}

// fused layer: block owns NB nodes; 8 half-waves sweep the block's CSR edge
// range, accumulate messages into LDS via ds atomics; then wave-per-node mixing.
__global__ __launch_bounds__(256, 2) void layer_kernel(
    const float* __restrict__ xin, float* __restrict__ xout,
    const float* __restrict__ rij, const float* __restrict__ Wbuf,
    const int* __restrict__ rowptr, const int* __restrict__ esort,
    const int* __restrict__ idx_i, const int* __restrict__ idx_j,
    const float* __restrict__ m1w, const float* __restrict__ m2w,
    const float* __restrict__ m3w,
    const float* __restrict__ gw, const float* __restrict__ gbias, int N) {

    __shared__ float dxacc[NB][9][F];   // accumulator, later reused as broadcast buf
    int tid = threadIdx.x;
    for (int k = tid; k < NB * 9 * F; k += 256) ((float*)dxacc)[k] = 0.0f;
    __syncthreads();

    int n0 = blockIdx.x * NB;
    int slot = tid >> 5;      // 0..7 edge slots
    int f = tid & 31;
    int nend = n0 + NB; if (nend > N) nend = N;
    int estart = rowptr[n0], eend = rowptr[nend];

    const float c0 = 0.28209479177387814f, c1 = 0.4886025119029199f;
    const float c2 = 1.0925484305920792f, c20 = 0.31539156525252005f;
    const float c22 = 0.5462742152960396f;

    for (int k = estart + slot; k < eend; k += 8) {
        int e = esort[k];
        int iloc = idx_i[e] - n0;
        const float* wp = Wbuf + (size_t)e * 96;
        float W0 = wp[f], W1 = wp[F + f], W2 = wp[2 * F + f];

        float rx = rij[3 * e + 0], ry = rij[3 * e + 1], rz = rij[3 * e + 2];
        float inv = 1.0f / sqrtf(rx * rx + ry * ry + rz * rz);
        rx *= inv; ry *= inv; rz *= inv;
        float T[9];
        T[0] = c0 * W0;
        T[1] = c1 * ry * W1;
        T[2] = c1 * rz * W1;
        T[3] = c1 * rx * W1;
        T[4] = c2 * rx * ry * W2;
        T[5] = c2 * ry * rz * W2;
        T[6] = c20 * (3.0f * rz * rz - 1.0f) * W2;
        T[7] = c2 * rx * rz * W2;
        T[8] = c22 * (rx * rx - ry * ry) * W2;

        int j = idx_j[e];
        const float* xjp = xin + (size_t)j * 288;
        float xj[9];
        #pragma unroll
        for (int m = 0; m < 9; m++) xj[m] = xjp[m * F + f];

        float msg[9];
        #pragma unroll
        for (int o = 0; o < 9; o++) {
            float acc = 0.0f;
            #pragma unroll
            for (int t = CG.off[o]; t < CG.off[o + 1]; t++)
                acc += (xj[CG.a[t]] * T[CG.b[t]]) * CG.v[t];
            msg[o] = acc;
        }

        #pragma unroll
        for (int o = 0; o < 9; o++)
            atomicAdd(&dxacc[iloc][o][f], msg[o]);
    }
    __syncthreads();

    // ---------- mixing: wave w <-> node n0+w; halves duplicate work ----------
    int w = tid >> 6;           // 0..3
    int h = (tid >> 5) & 1;
    int n = n0 + w;
    if (n < N) {
        float dxr[9];
        #pragma unroll
        for (int m = 0; m < 9; m++) dxr[m] = dxacc[w][m][f];

        float wreg[F];
        #pragma unroll
        for (int g = 0; g < F; g++) wreg[g] = m1w[g * F + f];
        float ddx[9];
        #pragma unroll
        for (int m = 0; m < 9; m++) ddx[m] = 0.0f;
        #pragma unroll
        for (int m = 0; m < 9; m++) {
            #pragma unroll
            for (int gb = 0; gb < 8; gb++) {
                float4 dv = *(const float4*)&dxacc[w][m][gb * 4];
                ddx[m] += dv.x * wreg[gb * 4 + 0];
                ddx[m] += dv.y * wreg[gb * 4 + 1];
                ddx[m] += dv.z * wreg[gb * 4 + 2];
                ddx[m] += dv.w * wreg[gb * 4 + 3];
            }
        }

        float tr[9];
        #pragma unroll
        for (int o = 0; o < 9; o++) {
            float acc = 0.0f;
            #pragma unroll
            for (int t = CG.off[o]; t < CG.off[o + 1]; t++)
                acc += dxr[CG.a[t]] * ddx[CG.b[t]] * CG.v[t];
            tr[o] = dxr[o] + acc;
        }

        // stage tr (overwrite dxacc row set for this node; wave-local -> no barrier)
        #pragma unroll
        for (int m = 0; m < 9; m++) dxacc[w][m][f] = tr[m];
        #pragma unroll
        for (int g = 0; g < F; g++) wreg[g] = m2w[g * F + f];
        float dx2[9];
        #pragma unroll
        for (int m = 0; m < 9; m++) dx2[m] = 0.0f;
        #pragma unroll
        for (int m = 0; m < 9; m++) {
            #pragma unroll
            for (int gb = 0; gb < 8; gb++) {
                float4 dv = *(const float4*)&dxacc[w][m][gb * 4];
                dx2[m] += dv.x * wreg[gb * 4 + 0];
                dx2[m] += dv.y * wreg[gb * 4 + 1];
                dx2[m] += dv.z * wreg[gb * 4 + 2];
                dx2[m] += dv.w * wreg[gb * 4 + 3];
            }
        }

        // stage dx2 for gate broadcast
        #pragma unroll
        for (int m = 0; m < 9; m++) dxacc[w][m][f] = dx2[m];
        float ga0 = gbias[f], ga1 = gbias[F + f], ga2 = gbias[2 * F + f];
        #pragma unroll
        for (int gb = 0; gb < 8; gb++) {
            float4 sv = *(const float4*)&dxacc[w][0][gb * 4];
            float sj[4] = {sv.x, sv.y, sv.z, sv.w};
            #pragma unroll
            for (int jj = 0; jj < 4; jj++) {
                int g = gb * 4 + jj;
                ga0 += sj[jj] * gw[g * 96 + f];
                ga1 += sj[jj] * gw[g * 96 + F + f];
                ga2 += sj[jj] * gw[g * 96 + 2 * F + f];
            }
        }
        float s0 = 1.0f / (1.0f + expf(-ga0));
        float s1 = 1.0f / (1.0f + expf(-ga1));
        float s2 = 1.0f / (1.0f + expf(-ga2));

        float gt[9];
        gt[0] = dx2[0] * s0;
        gt[1] = dx2[1] * s1; gt[2] = dx2[2] * s1; gt[3] = dx2[3] * s1;
        gt[4] = dx2[4] * s2; gt[5] = dx2[5] * s2; gt[6] = dx2[6] * s2;
        gt[7] = dx2[7] * s2; gt[8] = dx2[8] * s2;

        // stage gated, mix3, residual
        #pragma unroll
        for (int m = 0; m < 9; m++) dxacc[w][m][f] = gt[m];
        #pragma unroll
        for (int g = 0; g < F; g++) wreg[g] = m3w[g * F + f];
        float outv[9];
        #pragma unroll
        for (int m = 0; m < 9; m++) outv[m] = 0.0f;
        #pragma unroll
        for (int m = 0; m < 9; m++) {
            #pragma unroll
            for (int gb = 0; gb < 8; gb++) {
                float4 dv = *(const float4*)&dxacc[w][m][gb * 4];
                outv[m] += dv.x * wreg[gb * 4 + 0];
                outv[m] += dv.y * wreg[gb * 4 + 1];
                outv[m] += dv.z * wreg[gb * 4 + 2];
                outv[m] += dv.w * wreg[gb * 4 + 3];
            }
        }

        if (h == 0) {
            const float* xip = xin + (size_t)n * 288;
            float* xop = xout + (size_t)n * 288;
            #pragma unroll
            for (int m = 0; m < 9; m++)
                xop[m * F + f] = xip[m * F + f] + outv[m];
        }
    }
}

// ---------------- launch ----------------
extern "C" void kernel_launch(void* const* d_in, const int* in_sizes, int n_in,
                              void* d_out, int out_size, void* d_ws, size_t ws_size,
                              hipStream_t stream) {
    int N = in_sizes[0];
    int E = in_sizes[2];
    int L = in_sizes[5] / (NRBF * 3 * F);

    const int* Z = (const int*)d_in[0];
    const float* rij = (const float*)d_in[1];
    const int* idx_i = (const int*)d_in[2];
    const int* idx_j = (const int*)d_in[3];
    const float* emb = (const float*)d_in[4];
    const float* filt_w = (const float*)d_in[5];
    const float* filt_b = (const float*)d_in[6];
    const float* m1w = (const float*)d_in[7];
    const float* m2w = (const float*)d_in[8];
    const float* m3w = (const float*)d_in[9];
    const float* gw = (const float*)d_in[10];
    const float* gb = (const float*)d_in[11];

    float* ws = (float*)d_ws;
    float* Wbuf = ws;                          // E*96
    float* xalt = Wbuf + (size_t)E * 96;       // N*288
    int* deg = (int*)(xalt + (size_t)N * 288); // N
    int* rowptr = deg + N;                     // N+1
    int* cursor = rowptr + N + 1;              // N
    int* esort = cursor + N;                   // E

    float* bufs[2];
    bufs[0] = (L % 2 == 0) ? (float*)d_out : xalt;
    bufs[1] = (L % 2 == 0) ? xalt : (float*)d_out;

    init_x_kernel<<<(N * 288 + 255) / 256, 256, 0, stream>>>(bufs[0], Z, emb, N);

    hipMemsetAsync(deg, 0, (size_t)N * sizeof(int), stream);
    hist_kernel<<<(E + 255) / 256, 256, 0, stream>>>(idx_i, deg, E);
    scan_kernel<<<1, SCAN_T, 0, stream>>>(deg, rowptr, cursor, N);
    scatter_kernel<<<(E + 255) / 256, 256, 0, stream>>>(idx_i, cursor, esort, E);

    for (int li = 0; li < L; li++) {
        geomW_kernel<<<((size_t)E * 32 + 255) / 256, 256, 0, stream>>>(
            rij, filt_w + (size_t)li * NRBF * 96, filt_b + (size_t)li * 96, Wbuf, E);
        layer_kernel<<<(N + NB - 1) / NB, 256, 0, stream>>>(
            bufs[li % 2], bufs[(li + 1) % 2], rij, Wbuf,
            rowptr, esort, idx_i, idx_j,
            m1w + (size_t)li * F * F, m2w + (size_t)li * F * F,
            m3w + (size_t)li * F * F, gw + (size_t)li * F * 96,
            gb + (size_t)li * 96, N);
    }
}

// Round 5
// 255.241 us; speedup vs baseline: 2.1420x; 1.9865x over previous
//
#include <hip/hip_runtime.h>
#include <math.h>

// ---------------- problem constants ----------------
#define F 32
#define NRBF 20
#define MAXNZ 192
#define PI_F 3.14159265358979323846f

// ---------------- compile-time CG construction ----------------
struct CgCE {
    int cnt;
    int off[10];
    int a[MAXNZ];
    int b[MAXNZ];
    int lb[MAXNZ];
    float v[MAXNZ];
};

constexpr double cfact(int n) { double r = 1.0; for (int i = 2; i <= n; i++) r *= (double)i; return r; }
constexpr double csqrt(double x) {
    if (x <= 0.0) return 0.0;
    double r = x < 1.0 ? 1.0 : x;
    for (int i = 0; i < 80; i++) r = 0.5 * (r + x / r);
    return r;
}
constexpr int cabs_i(int x) { return x < 0 ? -x : x; }

constexpr double cg_c(int j1, int m1, int j2, int m2, int j3, int m3) {
    if (m1 + m2 != m3) return 0.0;
    if (j3 < cabs_i(j1 - j2) || j3 > j1 + j2) return 0.0;
    double pre = csqrt((2.0 * j3 + 1) * cfact(j1 + j2 - j3) * cfact(j1 - j2 + j3) *
                       cfact(-j1 + j2 + j3) / cfact(j1 + j2 + j3 + 1));
    pre *= csqrt(cfact(j3 + m3) * cfact(j3 - m3) * cfact(j1 - m1) * cfact(j1 + m1) *
                 cfact(j2 - m2) * cfact(j2 + m2));
    double s = 0.0;
    for (int k = 0; k <= j1 + j2 + j3; k++) {
        int d0 = k, d1 = j1 + j2 - j3 - k, d2 = j1 - m1 - k, d3 = j2 + m2 - k;
        int d4 = j3 - j2 + m1 + k, d5 = j3 - j1 - m2 + k;
        if (d0 < 0 || d1 < 0 || d2 < 0 || d3 < 0 || d4 < 0 || d5 < 0) continue;
        double t = cfact(d0) * cfact(d1) * cfact(d2) * cfact(d3) * cfact(d4) * cfact(d5);
        s += ((k & 1) ? -1.0 : 1.0) / t;
    }
    return pre * s;
}

struct U5 { double re[5][5]; double im[5][5]; };
constexpr U5 u_real(int l) {
    U5 u{};
    u.re[l][l] = 1.0;
    double s2 = 1.0 / csqrt(2.0);
    for (int m = 1; m <= l; m++) {
        double sgn = (m & 1) ? -1.0 : 1.0;
        u.re[l + m][l + m] = sgn * s2;
        u.re[l + m][l - m] = s2;
        u.im[l - m][l - m] = s2;
        u.im[l - m][l + m] = -sgn * s2;
    }
    return u;
}

struct Dense { double c[9][9][9]; };
constexpr Dense build_dense() {
    Dense D{};
    for (int l1 = 0; l1 <= 2; l1++)
        for (int l2 = 0; l2 <= 2; l2++)
            for (int l3 = 0; l3 <= 2; l3++) {
                if (l3 < cabs_i(l1 - l2) || l3 > l1 + l2) continue;
                U5 U1 = u_real(l1), U2 = u_real(l2), U3 = u_real(l3);
                int n1 = 2 * l1 + 1, n2 = 2 * l2 + 1, n3 = 2 * l3 + 1;
                for (int i = 0; i < n1; i++)
                    for (int j = 0; j < n2; j++) {
                        int k = (i - l1) + (j - l2) + l3;   // m3 = m1+m2
                        if (k < 0 || k >= n3) continue;
                        double C = cg_c(l1, i - l1, l2, j - l2, l3, k - l3);
                        if (C == 0.0) continue;
                        int as[2] = {i, n1 - 1 - i}, bs[2] = {j, n2 - 1 - j}, cs[2] = {k, n3 - 1 - k};
                        int na = (as[0] == as[1]) ? 1 : 2;
                        int nb = (bs[0] == bs[1]) ? 1 : 2;
                        int nc = (cs[0] == cs[1]) ? 1 : 2;
                        for (int ai = 0; ai < na; ai++)
                            for (int bi = 0; bi < nb; bi++)
                                for (int ci = 0; ci < nc; ci++) {
                                    int aa = as[ai], bb = bs[bi], cc = cs[ci];
                                    double xr = U1.re[aa][i], xi = U1.im[aa][i];
                                    double yr = U2.re[bb][j], yi = U2.im[bb][j];
                                    double tr = xr * yr - xi * yi;
                                    double ti = xr * yi + xi * yr;
                                    double zr = U3.re[cc][k], zi = -U3.im[cc][k]; // conj
                                    double add = (tr * zr - ti * zi) * C;
                                    if (add != 0.0)
                                        D.c[l1 * l1 + aa][l2 * l2 + bb][l3 * l3 + cc] += add;
                                }
                    }
            }
    return D;
}

constexpr CgCE build_cg() {
    CgCE t{};
    Dense D = build_dense();
    int cnt = 0;
    for (int o = 0; o < 9; o++) {
        t.off[o] = cnt;
        for (int aa = 0; aa < 9; aa++)
            for (int bb = 0; bb < 9; bb++) {
                double v = D.c[aa][bb][o];
                if (v > 1e-10 || v < -1e-10) {
                    t.a[cnt] = aa;
                    t.b[cnt] = bb;
                    t.lb[cnt] = (bb == 0) ? 0 : ((bb < 4) ? 1 : 2);
                    t.v[cnt] = (float)v;
                    cnt++;
                }
            }
    }
    t.off[9] = cnt;
    t.cnt = cnt;
    return t;
}

constexpr CgCE CG = build_cg();
static_assert(CG.cnt <= MAXNZ, "CG nnz overflow");
static_assert(CG.cnt > 0, "CG empty");

// ---------------- helpers ----------------
__device__ inline float readlane_f(float v, int lane) {
    union { float f; int i; } u; u.f = v;
    int r = __builtin_amdgcn_readlane(u.i, lane);
    union { int i; float f; } w; w.i = r;
    return w.f;
}

// ---------------- device kernels ----------------

__global__ void init_x_kernel(float* __restrict__ x, const int* __restrict__ Z,
                              const float* __restrict__ emb, int N) {
    int idx = blockIdx.x * blockDim.x + threadIdx.x;
    if (idx >= N * 288) return;
    int n = idx / 288, r = idx % 288;
    x[idx] = (r < F) ? emb[Z[n] * F + r] : 0.0f;
}

// ---- CSR build ----
__global__ void hist_kernel(const int* __restrict__ idx_i, int* __restrict__ deg, int E) {
    int e = blockIdx.x * blockDim.x + threadIdx.x;
    if (e < E) atomicAdd(&deg[idx_i[e]], 1);
}

#define SCAN_T 1024
__global__ __launch_bounds__(SCAN_T) void scan_kernel(
    const int* __restrict__ deg, int* __restrict__ rowptr,
    int* __restrict__ cursor, int N) {
    __shared__ int part[SCAN_T];
    int t = threadIdx.x;
    int per = (N + SCAN_T - 1) / SCAN_T;
    int lo = t * per, hi = lo + per;
    if (hi > N) hi = N;
    int s = 0;
    for (int i = lo; i < hi; i++) s += deg[i];
    part[t] = s;
    __syncthreads();
    for (int off = 1; off < SCAN_T; off <<= 1) {
        int v = (t >= off) ? part[t - off] : 0;
        __syncthreads();
        part[t] += v;
        __syncthreads();
    }
    int run = (t == 0) ? 0 : part[t - 1];
    for (int i = lo; i < hi; i++) {
        rowptr[i] = run;
        cursor[i] = run;
        run += deg[i];
    }
    if (t == SCAN_T - 1) rowptr[N] = run;
}

__global__ void scatter_kernel(const int* __restrict__ idx_i, int* __restrict__ cursor,
                               int* __restrict__ esort, int E) {
    int e = blockIdx.x * blockDim.x + threadIdx.x;
    if (e >= E) return;
    int p = atomicAdd(&cursor[idx_i[e]], 1);
    esort[p] = e;
}

// permute geometry into CSR-slot order (once per launch)
__global__ void perm_kernel(const int* __restrict__ esort, const int* __restrict__ idx_j,
                            const float* __restrict__ rij,
                            float* __restrict__ rijperm, float* __restrict__ dperm,
                            int* __restrict__ jperm, int E) {
    int k = blockIdx.x * blockDim.x + threadIdx.x;
    if (k >= E) return;
    int e = esort[k];
    jperm[k] = idx_j[e];
    float rx = rij[3 * e + 0], ry = rij[3 * e + 1], rz = rij[3 * e + 2];
    float d = sqrtf(rx * rx + ry * ry + rz * rz);
    float inv = 1.0f / d;
    rijperm[3 * k + 0] = rx * inv;
    rijperm[3 * k + 1] = ry * inv;
    rijperm[3 * k + 2] = rz * inv;
    dperm[k] = d;
}

// per-layer: Wperm[k][3][32] = (rad(d) @ fw + fb) * cut(d), in CSR order (streamed)
__global__ __launch_bounds__(256) void wperm_kernel(
    const float* __restrict__ dperm, const float* __restrict__ fw,
    const float* __restrict__ fbias, float* __restrict__ Wperm, int E) {
    int t = blockIdx.x * blockDim.x + threadIdx.x;
    int k = t >> 5, f = t & 31;
    if (k >= E) return;
    float d = dperm[k];
    const float step = 5.0f / 19.0f;
    const float coeff = -0.5f / (step * step);
    float W0 = fbias[f], W1 = fbias[F + f], W2 = fbias[2 * F + f];
    #pragma unroll
    for (int r = 0; r < NRBF; r++) {
        float tt = d - step * (float)r;
        float rv = expf(coeff * tt * tt);
        W0 += rv * fw[r * 96 + f];
        W1 += rv * fw[r * 96 + F + f];
        W2 += rv * fw[r * 96 + 2 * F + f];
    }
    float cu = (d < 5.0f) ? 0.5f * (cosf(d * PI_F / 5.0f) + 1.0f) : 0.0f;
    float* wp = Wperm + (size_t)k * 96;
    wp[f] = W0 * cu;
    wp[F + f] = W1 * cu;
    wp[2 * F + f] = W2 * cu;
}

// fused layer: wave per node; halves process edge pairs; register msg;
// shfl_xor merge; readlane-based mixing (no LDS, no atomics).
__global__ __launch_bounds__(256, 2) void layer_kernel(
    const float* __restrict__ xin, float* __restrict__ xout,
    const float* __restrict__ Wperm, const float* __restrict__ rijperm,
    const int* __restrict__ jperm, const int* __restrict__ rowptr,
    const float* __restrict__ m1w, const float* __restrict__ m2w,
    const float* __restrict__ m3w,
    const float* __restrict__ gw, const float* __restrict__ gbias, int N) {

    int lane = threadIdx.x & 63;
    int h = lane >> 5;          // half: which edge of the pair
    int f = lane & 31;          // feature
    int n = blockIdx.x * 4 + (threadIdx.x >> 6);
    if (n >= N) return;

    const float c0 = 0.28209479177387814f, c1 = 0.4886025119029199f;
    const float c2 = 1.0925484305920792f, c20 = 0.31539156525252005f;
    const float c22 = 0.5462742152960396f;

    float msg[9];
    #pragma unroll
    for (int o = 0; o < 9; o++) msg[o] = 0.0f;

    int k0 = rowptr[n], k1 = rowptr[n + 1];
    for (int k = k0 + h; k < k1; k += 2) {
        int j = jperm[k];                       // sequential (per half)
        const float* wp = Wperm + (size_t)k * 96;   // sequential stream
        float W0 = wp[f], W1 = wp[F + f], W2 = wp[2 * F + f];
        const float* rp = rijperm + (size_t)k * 3;  // sequential broadcast
        float ux = rp[0], uy = rp[1], uz = rp[2];   // already normalized

        float T[9];
        T[0] = c0 * W0;
        T[1] = c1 * uy * W1;
        T[2] = c1 * uz * W1;
        T[3] = c1 * ux * W1;
        T[4] = c2 * ux * uy * W2;
        T[5] = c2 * uy * uz * W2;
        T[6] = c20 * (3.0f * uz * uz - 1.0f) * W2;
        T[7] = c2 * ux * uz * W2;
        T[8] = c22 * (ux * ux - uy * uy) * W2;

        const float* xjp = xin + (size_t)j * 288;   // gather (L2-resident)
        float xj[9];
        #pragma unroll
        for (int m = 0; m < 9; m++) xj[m] = xjp[m * F + f];

        #pragma unroll
        for (int o = 0; o < 9; o++) {
            float acc = msg[o];
            #pragma unroll
            for (int t = CG.off[o]; t < CG.off[o + 1]; t++)
                acc += xj[CG.a[t]] * (T[CG.b[t]] * CG.v[t]);
            msg[o] = acc;
        }
    }

    // merge halves: both end with full per-node sum
    #pragma unroll
    for (int o = 0; o < 9; o++)
        msg[o] += __shfl_xor(msg[o], 32, 64);

    // ---------- mixing, all via readlane broadcasts (VALU pipe) ----------
    float wreg[F];

    // ddx = dx @ mix1
    #pragma unroll
    for (int g = 0; g < F; g++) wreg[g] = m1w[g * F + f];
    float ddx[9];
    #pragma unroll
    for (int m = 0; m < 9; m++) ddx[m] = 0.0f;
    #pragma unroll
    for (int g = 0; g < F; g++) {
        #pragma unroll
        for (int m = 0; m < 9; m++)
            ddx[m] += readlane_f(msg[m], g) * wreg[g];
    }

    // p = CG(dx, ddx); tr = dx + p
    float tr[9];
    #pragma unroll
    for (int o = 0; o < 9; o++) {
        float acc = 0.0f;
        #pragma unroll
        for (int t = CG.off[o]; t < CG.off[o + 1]; t++)
            acc += msg[CG.a[t]] * ddx[CG.b[t]] * CG.v[t];
        tr[o] = msg[o] + acc;
    }

    // dx2 = tr @ mix2
    #pragma unroll
    for (int g = 0; g < F; g++) wreg[g] = m2w[g * F + f];
    float dx2[9];
    #pragma unroll
    for (int m = 0; m < 9; m++) dx2[m] = 0.0f;
    #pragma unroll
    for (int g = 0; g < F; g++) {
        #pragma unroll
        for (int m = 0; m < 9; m++)
            dx2[m] += readlane_f(tr[m], g) * wreg[g];
    }

    // gate from dx2[0]
    float ga0 = gbias[f], ga1 = gbias[F + f], ga2 = gbias[2 * F + f];
    #pragma unroll
    for (int g = 0; g < F; g++) {
        float s = readlane_f(dx2[0], g);
        ga0 += s * gw[g * 96 + f];
        ga1 += s * gw[g * 96 + F + f];
        ga2 += s * gw[g * 96 + 2 * F + f];
    }
    float s0 = 1.0f / (1.0f + expf(-ga0));
    float s1 = 1.0f / (1.0f + expf(-ga1));
    float s2 = 1.0f / (1.0f + expf(-ga2));

    float gt[9];
    gt[0] = dx2[0] * s0;
    gt[1] = dx2[1] * s1; gt[2] = dx2[2] * s1; gt[3] = dx2[3] * s1;
    gt[4] = dx2[4] * s2; gt[5] = dx2[5] * s2; gt[6] = dx2[6] * s2;
    gt[7] = dx2[7] * s2; gt[8] = dx2[8] * s2;

    // out = gt @ mix3; residual
    #pragma unroll
    for (int g = 0; g < F; g++) wreg[g] = m3w[g * F + f];
    float outv[9];
    #pragma unroll
    for (int m = 0; m < 9; m++) outv[m] = 0.0f;
    #pragma unroll
    for (int g = 0; g < F; g++) {
        #pragma unroll
        for (int m = 0; m < 9; m++)
            outv[m] += readlane_f(gt[m], g) * wreg[g];
    }

    if (h == 0) {
        const float* xip = xin + (size_t)n * 288;
        float* xop = xout + (size_t)n * 288;
        #pragma unroll
        for (int m = 0; m < 9; m++)
            xop[m * F + f] = xip[m * F + f] + outv[m];
    }
}

// ---------------- launch ----------------
extern "C" void kernel_launch(void* const* d_in, const int* in_sizes, int n_in,
                              void* d_out, int out_size, void* d_ws, size_t ws_size,
                              hipStream_t stream) {
    int N = in_sizes[0];
    int E = in_sizes[2];
    int L = in_sizes[5] / (NRBF * 3 * F);

    const int* Z = (const int*)d_in[0];
    const float* rij = (const float*)d_in[1];
    const int* idx_i = (const int*)d_in[2];
    const int* idx_j = (const int*)d_in[3];
    const float* emb = (const float*)d_in[4];
    const float* filt_w = (const float*)d_in[5];
    const float* filt_b = (const float*)d_in[6];
    const float* m1w = (const float*)d_in[7];
    const float* m2w = (const float*)d_in[8];
    const float* m3w = (const float*)d_in[9];
    const float* gw = (const float*)d_in[10];
    const float* gb = (const float*)d_in[11];

    float* ws = (float*)d_ws;
    float* Wperm = ws;                                // 96E
    float* rijperm = Wperm + (size_t)E * 96;          // 3E
    float* dperm = rijperm + (size_t)E * 3;           // E
    float* xalt = dperm + E;                          // 288N
    int* jperm = (int*)(xalt + (size_t)N * 288);      // E
    int* deg = jperm + E;                             // N
    int* rowptr = deg + N;                            // N+1
    int* cursor = rowptr + N + 1;                     // N
    int* esort = cursor + N;                          // E

    float* bufs[2];
    bufs[0] = (L % 2 == 0) ? (float*)d_out : xalt;
    bufs[1] = (L % 2 == 0) ? xalt : (float*)d_out;

    init_x_kernel<<<(N * 288 + 255) / 256, 256, 0, stream>>>(bufs[0], Z, emb, N);

    hipMemsetAsync(deg, 0, (size_t)N * sizeof(int), stream);
    hist_kernel<<<(E + 255) / 256, 256, 0, stream>>>(idx_i, deg, E);
    scan_kernel<<<1, SCAN_T, 0, stream>>>(deg, rowptr, cursor, N);
    scatter_kernel<<<(E + 255) / 256, 256, 0, stream>>>(idx_i, cursor, esort, E);
    perm_kernel<<<(E + 255) / 256, 256, 0, stream>>>(esort, idx_j, rij,
                                                     rijperm, dperm, jperm, E);

    for (int li = 0; li < L; li++) {
        wperm_kernel<<<((size_t)E * 32 + 255) / 256, 256, 0, stream>>>(
            dperm, filt_w + (size_t)li * NRBF * 96, filt_b + (size_t)li * 96, Wperm, E);
        layer_kernel<<<(N + 3) / 4, 256, 0, stream>>>(
            bufs[li % 2], bufs[(li + 1) % 2], Wperm, rijperm, jperm, rowptr,
            m1w + (size_t)li * F * F, m2w + (size_t)li * F * F,
            m3w + (size_t)li * F * F, gw + (size_t)li * F * 96,
            gb + (size_t)li * 96, N);
    }
}